// Round 1
// baseline (263.931 us; speedup 1.0000x reference)
//
#include <hip/hip_runtime.h>
#include <stdint.h>

// Conv2DUF: 3x3 s1 p1 conv, x[32][128][56][56] f32, weight[1152][256] f32
// (k = c*9 + kh*3 + kw), bias[256] f32 -> out[32][256][56][56] f32.
// Strategy: bf16 implicit GEMM. M = 32*56*56 = 100352, N = 256, K = 1152.
//  ws layout: xt = bf16 x padded+transposed to [B][58][58][128] (NHWC, halo=0)
//             Wt = bf16 weight reordered to [9][256][128]  (K-contiguous)

#define C_INQ 128
#define C_OUTQ 256
#define HDIM 56
#define WDIM 56
#define BDIM 32
#define HP 58
#define WP 58
#define HWPIX (HDIM * WDIM)          // 3136
#define XT_ELEMS ((size_t)BDIM * HP * WP * C_INQ)   // 13,778,944
#define XT_BYTES (XT_ELEMS * 2)                     // 27,557,888

typedef __bf16 bf16x8 __attribute__((ext_vector_type(8)));
typedef unsigned short ushort8 __attribute__((ext_vector_type(8)));
typedef float floatx4 __attribute__((ext_vector_type(4)));

__device__ __forceinline__ unsigned short f2bf(float f) {
  union { float f; unsigned int u; } v; v.f = f;
  unsigned int u = v.u;
  unsigned int r = u + 0x7FFFu + ((u >> 16) & 1u);   // RNE, no NaN path (inputs are finite)
  return (unsigned short)(r >> 16);
}

// ---------------- kernel 1: x NCHW f32 -> xt [B][58][58][128] bf16, zero halo
__global__ __launch_bounds__(256) void pad_transpose_kernel(
    const float* __restrict__ x, unsigned short* __restrict__ xt) {
  const int blk = blockIdx.x;           // B*HP = 1856 blocks
  const int b = blk / HP;
  const int hp = blk % HP;
  const int t = threadIdx.x;
  unsigned short* __restrict__ xtrow = xt + (size_t)(b * HP + hp) * (WP * C_INQ);
  if (hp == 0 || hp == HP - 1) {
    for (int i = t; i < WP * C_INQ; i += 256) xtrow[i] = 0;
    return;
  }
  __shared__ float lds[C_INQ * 57];     // stride 57 breaks bank aliasing
  const int h = hp - 1;
  const float* __restrict__ xb = x + (size_t)b * C_INQ * HWPIX + h * WDIM;
  for (int i = t; i < C_INQ * WDIM; i += 256) {
    int c = i / WDIM, w = i % WDIM;
    lds[c * 57 + w] = xb[(size_t)c * HWPIX + w];     // coalesced along w
  }
  __syncthreads();
  for (int i = t; i < WP * C_INQ; i += 256) {
    int wp = i >> 7, c = i & 127;
    float v = (wp == 0 || wp == WP - 1) ? 0.0f : lds[c * 57 + (wp - 1)];
    xtrow[i] = f2bf(v);                              // coalesced along c
  }
}

// ---------------- kernel 2: weight [1152][256] f32 -> Wt [9][256][128] bf16
__global__ __launch_bounds__(256) void weight_transform_kernel(
    const float* __restrict__ w, unsigned short* __restrict__ wt) {
  int idx = blockIdx.x * 256 + threadIdx.x;   // 9*256*128 = 294912 exactly
  int khw = idx >> 15;
  int r = idx & 32767;
  int n = r >> 7;
  int c = r & 127;
  wt[idx] = f2bf(w[(size_t)(c * 9 + khw) * C_OUTQ + n]);
}

// ---------------- kernel 3: implicit GEMM, 128x128 tile, BK=32, bf16 MFMA
#define BM 128
#define BN 128
#define BK 32

__global__ __launch_bounds__(256, 2) void conv_gemm_kernel(
    const unsigned short* __restrict__ xt,
    const unsigned short* __restrict__ wt,
    const float* __restrict__ bias,
    float* __restrict__ out) {
  __shared__ __align__(16) unsigned short ldsA[BM * BK];  // [pixel][c] 8KB
  __shared__ __align__(16) unsigned short ldsB[BN * BK];  // [n][c]    8KB

  const int t = threadIdx.x;
  const int lane = t & 63;
  const int wave = t >> 6;
  const int tile_m = blockIdx.x;    // 784
  const int tile_n = blockIdx.y;    // 2
  const int n0 = tile_n * BN;

  // ---- staging precompute. chunk j = r*256 + t covers LDS bytes [16j,16j+16)
  // A: pixel = j>>2 (fixed per thread/round across all K-steps), cpart = (j&3)*8
  size_t baseA[2], baseB[2];
#pragma unroll
  for (int r = 0; r < 2; ++r) {
    int j = r * 256 + t;
    int pix = tile_m * BM + (j >> 2);
    int b = pix / HWPIX;
    int p = pix - b * HWPIX;
    int h = p / WDIM;
    int w = p - h * WDIM;
    baseA[r] = (size_t)((b * HP + h) * WP + w) * C_INQ + (j & 3) * 8;
    baseB[r] = (size_t)(n0 + (j >> 2)) * C_INQ + (j & 3) * 8;
  }
  // wave-uniform LDS dest bases (HW writes lane*16 past them)
  unsigned short* ldsA_dst[2] = { ldsA + wave * 512, ldsA + 2048 + wave * 512 };
  unsigned short* ldsB_dst[2] = { ldsB + wave * 512, ldsB + 2048 + wave * 512 };

  // ---- fragment read offsets (ushort units); row stride BK=32 us = 64B
  const int wm = (wave >> 1) * 64;
  const int wn = (wave & 1) * 64;
  const int mrow = lane & 15;
  const int quad = lane >> 4;
  int aoff[4], boff[4];
#pragma unroll
  for (int i = 0; i < 4; ++i) {
    aoff[i] = (wm + i * 16 + mrow) * BK + quad * 8;
    boff[i] = (wn + i * 16 + mrow) * BK + quad * 8;
  }

  floatx4 acc[4][4] = {};

  for (int s = 0; s < 36; ++s) {
    const int khw = s >> 2;
    const int c0 = (s & 3) * 32;
    const int kh = khw / 3;
    const int kw = khw - kh * 3;
    const size_t koffA = (size_t)(kh * WP + kw) * C_INQ + c0;   // wave-uniform
    const size_t koffB = (size_t)khw * (C_OUTQ * C_INQ) + c0;
#pragma unroll
    for (int r = 0; r < 2; ++r) {
      __builtin_amdgcn_global_load_lds(
          (const __attribute__((address_space(1))) unsigned int*)(xt + baseA[r] + koffA),
          (__attribute__((address_space(3))) unsigned int*)ldsA_dst[r], 16, 0, 0);
      __builtin_amdgcn_global_load_lds(
          (const __attribute__((address_space(1))) unsigned int*)(wt + baseB[r] + koffB),
          (__attribute__((address_space(3))) unsigned int*)ldsB_dst[r], 16, 0, 0);
    }
    __syncthreads();   // drains vmcnt -> LDS tiles valid

    bf16x8 afr[4], bfr[4];
#pragma unroll
    for (int i = 0; i < 4; ++i)
      afr[i] = __builtin_bit_cast(bf16x8, *(const ushort8*)(ldsA + aoff[i]));
#pragma unroll
    for (int i = 0; i < 4; ++i)
      bfr[i] = __builtin_bit_cast(bf16x8, *(const ushort8*)(ldsB + boff[i]));
#pragma unroll
    for (int i = 0; i < 4; ++i)
#pragma unroll
      for (int jn = 0; jn < 4; ++jn)
        acc[i][jn] = __builtin_amdgcn_mfma_f32_16x16x32_bf16(afr[i], bfr[jn], acc[i][jn], 0, 0, 0);

    __syncthreads();   // protect LDS before next overwrite
  }

  // ---- epilogue: C/D layout col = lane&15 (n), row = quad*4 + reg (m)
#pragma unroll
  for (int jn = 0; jn < 4; ++jn) {
    const int ng = n0 + wn + jn * 16 + mrow;
    const float bv = bias[ng];
#pragma unroll
    for (int i = 0; i < 4; ++i) {
      const int mbase = tile_m * BM + wm + i * 16 + quad * 4;
#pragma unroll
      for (int rg = 0; rg < 4; ++rg) {
        const int mg = mbase + rg;
        const int b = mg / HWPIX;
        const int p = mg - b * HWPIX;
        out[(size_t)b * (C_OUTQ * HWPIX) + (size_t)ng * HWPIX + p] = acc[i][jn][rg] + bv;
      }
    }
  }
}

extern "C" void kernel_launch(void* const* d_in, const int* in_sizes, int n_in,
                              void* d_out, int out_size, void* d_ws, size_t ws_size,
                              hipStream_t stream) {
  const float* x    = (const float*)d_in[0];
  const float* w    = (const float*)d_in[1];
  const float* bias = (const float*)d_in[2];
  float* out = (float*)d_out;

  unsigned short* xt = (unsigned short*)d_ws;
  unsigned short* wt = (unsigned short*)((char*)d_ws + XT_BYTES);  // + 589,824 B

  hipLaunchKernelGGL(pad_transpose_kernel, dim3(BDIM * HP), dim3(256), 0, stream, x, xt);
  hipLaunchKernelGGL(weight_transform_kernel, dim3(1152), dim3(256), 0, stream, w, wt);
  hipLaunchKernelGGL(conv_gemm_kernel, dim3(784, 2), dim3(256), 0, stream, xt, wt, bias, out);
}

// Round 2
// 236.561 us; speedup vs baseline: 1.1157x; 1.1157x over previous
//
#include <hip/hip_runtime.h>
#include <stdint.h>

// Conv2DUF: 3x3 s1 p1 conv, x[32][128][56][56] f32, weight[1152][256] f32
// (k = c*9 + kh*3 + kw), bias[256] f32 -> out[32][256][56][56] f32.
// bf16 implicit GEMM: M = 32*56*56 = 100352, N = 256, K = 1152.
//  ws: xt = bf16 x padded+transposed [B][58][58][128] (NHWC, halo=0)
//      wt = bf16 weight reordered    [9][256][128]    (K-contiguous)

#define C_INQ 128
#define C_OUTQ 256
#define HDIM 56
#define WDIM 56
#define BDIM 32
#define HP 58
#define WP 58
#define HWPIX (HDIM * WDIM)          // 3136
#define XT_ELEMS ((size_t)BDIM * HP * WP * C_INQ)   // 13,778,944
#define XT_BYTES (XT_ELEMS * 2)                     // 27,557,888

typedef __bf16 bf16x8 __attribute__((ext_vector_type(8)));
typedef unsigned short ushort8 __attribute__((ext_vector_type(8)));
typedef float floatx4 __attribute__((ext_vector_type(4)));

__device__ __forceinline__ unsigned short f2bf(float f) {
  union { float f; unsigned int u; } v; v.f = f;
  unsigned int u = v.u;
  unsigned int r = u + 0x7FFFu + ((u >> 16) & 1u);   // RNE (finite inputs)
  return (unsigned short)(r >> 16);
}
__device__ __forceinline__ unsigned int pack2(float a, float b) {
  return (unsigned int)f2bf(a) | ((unsigned int)f2bf(b) << 16);
}

// ---------------- kernel 1: x NCHW f32 -> xt [B][58][58][128] bf16, zero halo
__global__ __launch_bounds__(256) void pad_transpose_kernel(
    const float* __restrict__ x, unsigned short* __restrict__ xt) {
  const int blk = blockIdx.x;           // B*HP = 1856 blocks
  const int b = blk / HP;
  const int hp = blk % HP;
  const int t = threadIdx.x;
  uint4* __restrict__ xtrow4 = (uint4*)(xt + (size_t)(b * HP + hp) * (WP * C_INQ));
  if (hp == 0 || hp == HP - 1) {        // halo rows: 928 uint4 of zeros
    for (int i = t; i < 928; i += 256) xtrow4[i] = make_uint4(0, 0, 0, 0);
    return;
  }
  __shared__ float lds[C_INQ * 62];     // [c][w], stride 62 (2-way banks = free)
  const int h = hp - 1;
  const float* __restrict__ xb = x + (size_t)b * C_INQ * HWPIX + (size_t)h * WDIM;
  // phase 1: 128 c * 14 float4 along w (aligned: 224-byte rows)
  for (int i = t; i < 1792; i += 256) {
    int c = i / 14, w4 = (i - c * 14) * 4;
    const float4 v = *(const float4*)(xb + (size_t)c * HWPIX + w4);
    float* d = lds + c * 62 + w4;
    *(float2*)d = make_float2(v.x, v.y);
    *(float2*)(d + 2) = make_float2(v.z, v.w);
  }
  __syncthreads();
  // phase 2: 928 chunks of 8 bf16 (uint4); chunk j: wp = j>>4, c8 = (j&15)*8
  for (int j = t; j < 928; j += 256) {
    int wp = j >> 4, c8 = (j & 15) * 8;
    uint4 o;
    if (wp == 0 || wp == WP - 1) {
      o = make_uint4(0, 0, 0, 0);
    } else {
      const float* s = lds + c8 * 62 + (wp - 1);
      o.x = pack2(s[0],   s[62]);
      o.y = pack2(s[124], s[186]);
      o.z = pack2(s[248], s[310]);
      o.w = pack2(s[372], s[434]);
    }
    xtrow4[j] = o;
  }
}

// ---------------- kernel 2: weight [1152][256] f32 -> wt [9][256][128] bf16
// Tiled transpose: block = (khw, n-chunk of 64, c-chunk of 32). 144 blocks.
__global__ __launch_bounds__(256) void weight_transform_kernel(
    const float* __restrict__ w, unsigned short* __restrict__ wt) {
  const int bx = blockIdx.x;
  const int khw = bx >> 4;
  const int r4 = bx & 15;
  const int n0w = (r4 >> 2) * 64;
  const int c32 = (r4 & 3) * 32;
  const int t = threadIdx.x;
  __shared__ float lds[32 * 66];        // [c][n], stride 66
  // phase 1: coalesced reads along n (256B rows)
#pragma unroll
  for (int r = 0; r < 8; ++r) {
    int idx = r * 256 + t;              // 32*64 = 2048
    int n = idx & 63, c = idx >> 6;
    lds[c * 66 + n] = w[(size_t)((c32 + c) * 9 + khw) * C_OUTQ + n0w + n];
  }
  __syncthreads();
  // phase 2: one uint4 (8 c) per thread: n = t>>2, c8 group = t&3
  {
    int n = t >> 2, c8 = (t & 3) * 8;
    const float* s = lds + c8 * 66 + n;
    uint4 o;
    o.x = pack2(s[0],   s[66]);
    o.y = pack2(s[132], s[198]);
    o.z = pack2(s[264], s[330]);
    o.w = pack2(s[396], s[462]);
    *(uint4*)(wt + (size_t)khw * (C_OUTQ * C_INQ) + (size_t)(n0w + n) * C_INQ + c32 + c8) = o;
  }
}

// ---------------- kernel 3: implicit GEMM, 128x128 tile, BK=64, swizzled LDS
#define BM 128
#define BN 128
#define BK 64
#define STEPS 18

__global__ __launch_bounds__(256) void conv_gemm_kernel(
    const unsigned short* __restrict__ xt,
    const unsigned short* __restrict__ wt,
    const float* __restrict__ bias,
    float* __restrict__ out) {
  // granule = 16B (8 ushorts). data(row,kpart) lives at slot row*8 + (kpart^(row&7))
  __shared__ __align__(16) unsigned short ldsA[BM * BK];  // 16KB
  __shared__ __align__(16) unsigned short ldsB[BN * BK];  // 16KB

  const int t = threadIdx.x;
  const int lane = t & 63;
  const int wave = t >> 6;
  const int tile_m = blockIdx.x;    // 784
  const int tile_n = blockIdx.y;    // 2
  const int n0 = tile_n * BN;

  // staging: round r stages granule g = r*256 + t (A and B each, 4 rounds)
  int gbaseA[4], gbaseB[4];
#pragma unroll
  for (int r = 0; r < 4; ++r) {
    int g = r * 256 + t;
    int row = g >> 3;
    int kpart = (g & 7) ^ (row & 7);       // swizzle inverse
    int pix = tile_m * BM + row;
    int b = pix / HWPIX;
    int p = pix - b * HWPIX;
    int h = p / WDIM;
    int w = p - h * WDIM;
    gbaseA[r] = ((b * HP + h) * WP + w) * C_INQ + kpart * 8;
    gbaseB[r] = (n0 + row) * C_INQ + kpart * 8;
  }
  // wave-uniform LDS dest bases (HW adds lane*16 bytes)
  unsigned short* ldsA_dst[4];
  unsigned short* ldsB_dst[4];
#pragma unroll
  for (int r = 0; r < 4; ++r) {
    ldsA_dst[r] = ldsA + (r * 256 + wave * 64) * 8;
    ldsB_dst[r] = ldsB + (r * 256 + wave * 64) * 8;
  }

  // fragment read offsets (ushorts): slot*8 = row*64 + ((u*4+quad)^(mrow&7))*8
  const int wm = (wave >> 1) * 64;
  const int wn = (wave & 1) * 64;
  const int mrow = lane & 15;
  const int quad = lane >> 4;
  const int xorv = mrow & 7;

  floatx4 acc[4][4] = {};

  for (int s = 0; s < STEPS; ++s) {
    const int khw = s >> 1;
    const int c0 = (s & 1) * 64;
    const int kh = khw / 3;
    const int kw = khw - kh * 3;
    const int koffA = (kh * WP + kw) * C_INQ + c0;           // wave-uniform
    const int koffB = khw * (C_OUTQ * C_INQ) + c0;
#pragma unroll
    for (int r = 0; r < 4; ++r) {
      __builtin_amdgcn_global_load_lds(
          (const __attribute__((address_space(1))) unsigned int*)(xt + gbaseA[r] + koffA),
          (__attribute__((address_space(3))) unsigned int*)ldsA_dst[r], 16, 0, 0);
      __builtin_amdgcn_global_load_lds(
          (const __attribute__((address_space(1))) unsigned int*)(wt + gbaseB[r] + koffB),
          (__attribute__((address_space(3))) unsigned int*)ldsB_dst[r], 16, 0, 0);
    }
    __syncthreads();   // drains vmcnt -> LDS tiles valid

#pragma unroll
    for (int u = 0; u < 2; ++u) {
      bf16x8 afr[4], bfr[4];
#pragma unroll
      for (int i = 0; i < 4; ++i) {
        int off = (wm + i * 16 + mrow) * 64 + (((u * 4 + quad) ^ xorv) * 8);
        afr[i] = __builtin_bit_cast(bf16x8, *(const ushort8*)(ldsA + off));
      }
#pragma unroll
      for (int jn = 0; jn < 4; ++jn) {
        int off = (wn + jn * 16 + mrow) * 64 + (((u * 4 + quad) ^ xorv) * 8);
        bfr[jn] = __builtin_bit_cast(bf16x8, *(const ushort8*)(ldsB + off));
      }
#pragma unroll
      for (int i = 0; i < 4; ++i)
#pragma unroll
        for (int jn = 0; jn < 4; ++jn)
          acc[i][jn] = __builtin_amdgcn_mfma_f32_16x16x32_bf16(afr[i], bfr[jn], acc[i][jn], 0, 0, 0);
    }
    __syncthreads();   // protect LDS before next step's staging
  }

  // epilogue: C/D layout col(n) = lane&15, row(m) = quad*4 + reg.
  // 4 consecutive pixels per lane -> one float4 store (3136 % 4 == 0: no
  // batch crossing inside a quad).
  float bv[4];
#pragma unroll
  for (int jn = 0; jn < 4; ++jn) bv[jn] = bias[n0 + wn + jn * 16 + mrow];
#pragma unroll
  for (int i = 0; i < 4; ++i) {
    const int mbase = tile_m * BM + wm + i * 16 + quad * 4;
    const int b = mbase / HWPIX;
    const int p = mbase - b * HWPIX;
    float* obase = out + (size_t)b * (C_OUTQ * HWPIX) + p;
#pragma unroll
    for (int jn = 0; jn < 4; ++jn) {
      const int ng = n0 + wn + jn * 16 + mrow;
      floatx4 v = acc[i][jn];
      v[0] += bv[jn]; v[1] += bv[jn]; v[2] += bv[jn]; v[3] += bv[jn];
      *(floatx4*)(obase + (size_t)ng * HWPIX) = v;
    }
  }
}

extern "C" void kernel_launch(void* const* d_in, const int* in_sizes, int n_in,
                              void* d_out, int out_size, void* d_ws, size_t ws_size,
                              hipStream_t stream) {
  const float* x    = (const float*)d_in[0];
  const float* w    = (const float*)d_in[1];
  const float* bias = (const float*)d_in[2];
  float* out = (float*)d_out;

  unsigned short* xt = (unsigned short*)d_ws;
  unsigned short* wt = (unsigned short*)((char*)d_ws + XT_BYTES);  // +589,824 B

  hipLaunchKernelGGL(pad_transpose_kernel, dim3(BDIM * HP), dim3(256), 0, stream, x, xt);
  hipLaunchKernelGGL(weight_transform_kernel, dim3(144), dim3(256), 0, stream, w, wt);
  hipLaunchKernelGGL(conv_gemm_kernel, dim3(784, 2), dim3(256), 0, stream, xt, wt, bias, out);
}

// Round 3
// 214.825 us; speedup vs baseline: 1.2286x; 1.1012x over previous
//
#include <hip/hip_runtime.h>
#include <stdint.h>

// Conv2DUF: 3x3 s1 p1 conv, x[32][128][56][56] f32, weight[1152][256] f32
// (k = c*9 + kh*3 + kw), bias[256] f32 -> out[32][256][56][56] f32.
// bf16 implicit GEMM: M = 32*56*56 = 100352, N = 256, K = 1152.
//  ws: xt = bf16 x padded+transposed [B][58][58][128] (NHWC, halo=0)
//      wt = bf16 weight reordered    [9][256][128]    (K-contiguous)
// R2: BN=256 (full N per block): grid 784, A staged once, 64 MFMA/barrier/wave.

#define C_INQ 128
#define C_OUTQ 256
#define HDIM 56
#define WDIM 56
#define BDIM 32
#define HP 58
#define WP 58
#define HWPIX (HDIM * WDIM)          // 3136
#define XT_ELEMS ((size_t)BDIM * HP * WP * C_INQ)   // 13,778,944
#define XT_BYTES (XT_ELEMS * 2)                     // 27,557,888

typedef __bf16 bf16x8 __attribute__((ext_vector_type(8)));
typedef unsigned short ushort8 __attribute__((ext_vector_type(8)));
typedef float floatx4 __attribute__((ext_vector_type(4)));

__device__ __forceinline__ unsigned short f2bf(float f) {
  union { float f; unsigned int u; } v; v.f = f;
  unsigned int u = v.u;
  unsigned int r = u + 0x7FFFu + ((u >> 16) & 1u);   // RNE (finite inputs)
  return (unsigned short)(r >> 16);
}
__device__ __forceinline__ unsigned int pack2(float a, float b) {
  return (unsigned int)f2bf(a) | ((unsigned int)f2bf(b) << 16);
}

// ---------------- kernel 1: x NCHW f32 -> xt [B][58][58][128] bf16, zero halo
__global__ __launch_bounds__(256) void pad_transpose_kernel(
    const float* __restrict__ x, unsigned short* __restrict__ xt) {
  const int blk = blockIdx.x;           // B*HP = 1856 blocks
  const int b = blk / HP;
  const int hp = blk % HP;
  const int t = threadIdx.x;
  uint4* __restrict__ xtrow4 = (uint4*)(xt + (size_t)(b * HP + hp) * (WP * C_INQ));
  if (hp == 0 || hp == HP - 1) {        // halo rows: 928 uint4 of zeros
    for (int i = t; i < 928; i += 256) xtrow4[i] = make_uint4(0, 0, 0, 0);
    return;
  }
  __shared__ float lds[C_INQ * 62];     // [c][w], stride 62 (2-way banks = free)
  const int h = hp - 1;
  const float* __restrict__ xb = x + (size_t)b * C_INQ * HWPIX + (size_t)h * WDIM;
  // phase 1: 128 c * 14 float4 along w (aligned: 224-byte rows)
  for (int i = t; i < 1792; i += 256) {
    int c = i / 14, w4 = (i - c * 14) * 4;
    const float4 v = *(const float4*)(xb + (size_t)c * HWPIX + w4);
    float* d = lds + c * 62 + w4;
    *(float2*)d = make_float2(v.x, v.y);
    *(float2*)(d + 2) = make_float2(v.z, v.w);
  }
  __syncthreads();
  // phase 2: 928 chunks of 8 bf16 (uint4); chunk j: wp = j>>4, c8 = (j&15)*8
  for (int j = t; j < 928; j += 256) {
    int wp = j >> 4, c8 = (j & 15) * 8;
    uint4 o;
    if (wp == 0 || wp == WP - 1) {
      o = make_uint4(0, 0, 0, 0);
    } else {
      const float* s = lds + c8 * 62 + (wp - 1);
      o.x = pack2(s[0],   s[62]);
      o.y = pack2(s[124], s[186]);
      o.z = pack2(s[248], s[310]);
      o.w = pack2(s[372], s[434]);
    }
    xtrow4[j] = o;
  }
}

// ---------------- kernel 2: weight [1152][256] f32 -> wt [9][256][128] bf16
__global__ __launch_bounds__(256) void weight_transform_kernel(
    const float* __restrict__ w, unsigned short* __restrict__ wt) {
  const int bx = blockIdx.x;
  const int khw = bx >> 4;
  const int r4 = bx & 15;
  const int n0w = (r4 >> 2) * 64;
  const int c32 = (r4 & 3) * 32;
  const int t = threadIdx.x;
  __shared__ float lds[32 * 66];        // [c][n], stride 66
#pragma unroll
  for (int r = 0; r < 8; ++r) {
    int idx = r * 256 + t;              // 32*64 = 2048
    int n = idx & 63, c = idx >> 6;
    lds[c * 66 + n] = w[(size_t)((c32 + c) * 9 + khw) * C_OUTQ + n0w + n];
  }
  __syncthreads();
  {
    int n = t >> 2, c8 = (t & 3) * 8;
    const float* s = lds + c8 * 66 + n;
    uint4 o;
    o.x = pack2(s[0],   s[66]);
    o.y = pack2(s[132], s[198]);
    o.z = pack2(s[264], s[330]);
    o.w = pack2(s[396], s[462]);
    *(uint4*)(wt + (size_t)khw * (C_OUTQ * C_INQ) + (size_t)(n0w + n) * C_INQ + c32 + c8) = o;
  }
}

// ---------------- kernel 3: implicit GEMM, 128x256 tile, BK=64, swizzled LDS
#define BM 128
#define BN 256
#define BK 64
#define STEPS 18

__global__ __launch_bounds__(256, 2) void conv_gemm_kernel(
    const unsigned short* __restrict__ xt,
    const unsigned short* __restrict__ wt,
    const float* __restrict__ bias,
    float* __restrict__ out) {
  // granule = 16B (8 ushorts). data(row,kpart) at slot row*8 + (kpart^(row&7))
  __shared__ __align__(16) unsigned short ldsA[BM * BK];  // 16KB
  __shared__ __align__(16) unsigned short ldsB[BN * BK];  // 32KB

  const int t = threadIdx.x;
  const int lane = t & 63;
  const int wave = t >> 6;
  const int tile_m = blockIdx.x;    // 784

  // staging: A rounds 0..3, B rounds 0..7; round r stages granule g = r*256+t
  int gbaseA[4], gbaseB[8];
#pragma unroll
  for (int r = 0; r < 4; ++r) {
    int g = r * 256 + t;
    int row = g >> 3;
    int kpart = (g & 7) ^ (row & 7);       // swizzle inverse
    int pix = tile_m * BM + row;
    int b = pix / HWPIX;
    int p = pix - b * HWPIX;
    int h = p / WDIM;
    int w = p - h * WDIM;
    gbaseA[r] = ((b * HP + h) * WP + w) * C_INQ + kpart * 8;
  }
#pragma unroll
  for (int r = 0; r < 8; ++r) {
    int g = r * 256 + t;
    int row = g >> 3;                      // = n (BN == C_OUTQ)
    int kpart = (g & 7) ^ (row & 7);
    gbaseB[r] = row * C_INQ + kpart * 8;
  }

  // fragment geometry: wave grid 2x2 -> wave tile 64m x 128n
  const int wm = (wave >> 1) * 64;
  const int wn = (wave & 1) * 128;
  const int mrow = lane & 15;
  const int quad = lane >> 4;
  const int xorv = mrow & 7;

  floatx4 acc[4][8] = {};

  for (int s = 0; s < STEPS; ++s) {
    const int khw = s >> 1;
    const int c0 = (s & 1) * 64;
    const int kh = khw / 3;
    const int kw = khw - kh * 3;
    const int koffA = (kh * WP + kw) * C_INQ + c0;           // wave-uniform
    const int koffB = khw * (C_OUTQ * C_INQ) + c0;
#pragma unroll
    for (int r = 0; r < 4; ++r)
      __builtin_amdgcn_global_load_lds(
          (const __attribute__((address_space(1))) unsigned int*)(xt + gbaseA[r] + koffA),
          (__attribute__((address_space(3))) unsigned int*)(ldsA + (r * 256 + wave * 64) * 8),
          16, 0, 0);
#pragma unroll
    for (int r = 0; r < 8; ++r)
      __builtin_amdgcn_global_load_lds(
          (const __attribute__((address_space(1))) unsigned int*)(wt + gbaseB[r] + koffB),
          (__attribute__((address_space(3))) unsigned int*)(ldsB + (r * 256 + wave * 64) * 8),
          16, 0, 0);
    __syncthreads();   // drains vmcnt -> LDS tiles valid

#pragma unroll
    for (int u = 0; u < 2; ++u) {
      const int kx = ((u * 4 + quad) ^ xorv) * 8;
      bf16x8 afr[4], bfr[8];
#pragma unroll
      for (int i = 0; i < 4; ++i)
        afr[i] = __builtin_bit_cast(bf16x8,
                 *(const ushort8*)(ldsA + (wm + i * 16 + mrow) * 64 + kx));
#pragma unroll
      for (int jn = 0; jn < 8; ++jn)
        bfr[jn] = __builtin_bit_cast(bf16x8,
                  *(const ushort8*)(ldsB + (wn + jn * 16 + mrow) * 64 + kx));
#pragma unroll
      for (int i = 0; i < 4; ++i)
#pragma unroll
        for (int jn = 0; jn < 8; ++jn)
          acc[i][jn] = __builtin_amdgcn_mfma_f32_16x16x32_bf16(afr[i], bfr[jn], acc[i][jn], 0, 0, 0);
    }
    __syncthreads();   // protect LDS before next step's staging
  }

  // epilogue: C/D layout col(n) = lane&15, row(m) = quad*4 + reg.
  // 4 consecutive pixels per lane -> one float4 store (3136 % 4 == 0).
  float bv[8];
#pragma unroll
  for (int jn = 0; jn < 8; ++jn) bv[jn] = bias[wn + jn * 16 + mrow];
#pragma unroll
  for (int i = 0; i < 4; ++i) {
    const int mbase = tile_m * BM + wm + i * 16 + quad * 4;
    const int b = mbase / HWPIX;
    const int p = mbase - b * HWPIX;
    float* obase = out + (size_t)b * (C_OUTQ * HWPIX) + p;
#pragma unroll
    for (int jn = 0; jn < 8; ++jn) {
      const int ng = wn + jn * 16 + mrow;
      floatx4 v = acc[i][jn];
      v[0] += bv[jn]; v[1] += bv[jn]; v[2] += bv[jn]; v[3] += bv[jn];
      *(floatx4*)(obase + (size_t)ng * HWPIX) = v;
    }
  }
}

extern "C" void kernel_launch(void* const* d_in, const int* in_sizes, int n_in,
                              void* d_out, int out_size, void* d_ws, size_t ws_size,
                              hipStream_t stream) {
  const float* x    = (const float*)d_in[0];
  const float* w    = (const float*)d_in[1];
  const float* bias = (const float*)d_in[2];
  float* out = (float*)d_out;

  unsigned short* xt = (unsigned short*)d_ws;
  unsigned short* wt = (unsigned short*)((char*)d_ws + XT_BYTES);  // +589,824 B

  hipLaunchKernelGGL(pad_transpose_kernel, dim3(BDIM * HP), dim3(256), 0, stream, x, xt);
  hipLaunchKernelGGL(weight_transform_kernel, dim3(144), dim3(256), 0, stream, w, wt);
  hipLaunchKernelGGL(conv_gemm_kernel, dim3(784), dim3(256), 0, stream, xt, wt, bias, out);
}